// Round 17
// baseline (183.497 us; speedup 1.0000x reference)
//
#include <hip/hip_runtime.h>

typedef _Float16 f16x8 __attribute__((ext_vector_type(8)));
typedef _Float16 f16x4 __attribute__((ext_vector_type(4)));
typedef float f32x4 __attribute__((ext_vector_type(4)));

static constexpr int S = 4;
static constexpr int NATOMS = 32768;
static constexpr int FIN = 512;
static constexpr int H = 256;
static constexpr int BM = 128;   // atoms per block
static constexpr int XSTR = 36;  // 32 fp16 + 4 pad (72B rows: 2-way banks, free)
static constexpr int HSTR = 264; // h plane: 256 cols + 8 pad fp16 (528B rows, 2-way)
static constexpr int NSTRUCT = 512;
static constexpr int RBLK = 128;
static constexpr int APB = (S * NATOMS) / RBLK;  // 1024

// ---- merged weight packing: fp32 [S][K][H] -> per-(s,wn) consumption-order fp16
// Stream layout: [s*4 + (ntile>>2)][p][lane][8]; p = kt*4 + (ntile&3).
__global__ void pack_all(const float* __restrict__ W1, const float* __restrict__ W2,
                         const float* __restrict__ W3,
                         _Float16* __restrict__ W1p, _Float16* __restrict__ W2p,
                         _Float16* __restrict__ W3p) {
    int bid = blockIdx.x;
    const float* W;
    _Float16* dst;
    int KT, base;
    if (bid < 2048)      { W = W1; dst = W1p; KT = 16; base = 0; }
    else if (bid < 3072) { W = W2; dst = W2p; KT = 8;  base = 2048; }
    else                 { W = W3; dst = W3p; KT = 8;  base = 3072; }
    int idx = (bid - base) * 256 + threadIdx.x;
    int j = idx & 7;
    int lane = (idx >> 3) & 63;
    int rest = idx >> 9;
    int kt = rest % KT;
    int t2 = rest / KT;            // s*16 + ntile
    int K = KT * 32;
    int k = kt * 32 + (lane >> 4) * 8 + j;
    int ntile = t2 & 15;
    int s = t2 >> 4;
    int n = ntile * 16 + (lane & 15);
    int p = kt * 4 + (ntile & 3);
    size_t o = ((((size_t)(s * 4 + (ntile >> 2))) * (KT * 4) + p) * 64 + lane) * 8 + j;
    dst[o] = (_Float16)W[((size_t)s * K + k) * H + n];
}

__global__ __launch_bounds__(512, 2) void fused_mlp(
    const float* __restrict__ X,
    const _Float16* __restrict__ W1p, const _Float16* __restrict__ W2p,
    const _Float16* __restrict__ W3p,
    const float* __restrict__ b1, const float* __restrict__ b2,
    const float* __restrict__ b3,
    const float* __restrict__ W4, const float* __restrict__ b4,
    float* __restrict__ Eout)
{
    // union: X fp16 triple buffer [3][128][36] (27648B) aliased by h fp16 plane
    // [128][264] (67584B). h written only after all layer-1 LDS reads are done.
    __shared__ _Float16 smem[BM * HSTR];
    __shared__ float e_lds[4][BM];

    const int s = blockIdx.y;
    const int tile = blockIdx.x;
    const int tid = threadIdx.x;
    const int rw = __builtin_amdgcn_readfirstlane(tid >> 6);
    const int wm = rw >> 2;        // 0..1: M-half (64 atoms)
    const int wn = rw & 3;         // 0..3: 64-col slice of H
    const int lane = tid & 63;
    const int g = lane >> 4;
    const int mh = lane & 15;
    const int srow = tid >> 2;     // staging row (128 rows, 4 threads/row)
    const int cq = tid & 3;        // staging col group (8 floats)

    const float* Xb = X + (size_t)(s * NATOMS + tile * BM) * FIN;
    _Float16* hb = smem;

    const _Float16* Wb1 = W1p + ((size_t)(s * 4 + wn)) * (64 * 512) + lane * 8;
    const _Float16* Wb2 = W2p + ((size_t)(s * 4 + wn)) * (32 * 512) + lane * 8;
    const _Float16* Wb3 = W3p + ((size_t)(s * 4 + wn)) * (32 * 512) + lane * 8;

    f32x4 acc[4][4];
#pragma unroll
    for (int i = 0; i < 4; ++i)
#pragma unroll
        for (int j = 0; j < 4; ++j)
            acc[i][j] = f32x4{0.f, 0.f, 0.f, 0.f};

    // ---- staging: global->reg (f32) -> cvt once -> LDS (f16) ----
    f32x4 ld[3][2];
    auto loadc = [&](int slot, int c) {
        const float* p = Xb + (size_t)srow * FIN + c * 32 + cq * 8;
        ld[slot][0] = *(const f32x4*)(p);
        ld[slot][1] = *(const f32x4*)(p + 4);
    };
    auto storec = [&](int slot, int c) {
        _Float16* xb = smem + (c % 3) * (BM * XSTR);
#pragma unroll
        for (int i = 0; i < 2; ++i) {
            f16x4 v;
#pragma unroll
            for (int j = 0; j < 4; ++j) v[j] = (_Float16)ld[slot][i][j];
            *(f16x4*)(xb + srow * XSTR + cq * 8 + i * 4) = v;
        }
    };

    // ---- one-iteration-ahead operand pipeline (statically indexed: rule #20) ----
    f16x8 areg[2][4];   // A-fragments for chunk parity
    f16x8 wr[2][4];     // B-fragments for chunk parity
    auto aread = [&](int c) {
        const _Float16* xb = smem + (c % 3) * (BM * XSTR);
#pragma unroll
        for (int mt = 0; mt < 4; ++mt)
            areg[c & 1][mt] = *(const f16x8*)(xb + (wm * 64 + mt * 16 + mh) * XSTR + g * 8);
    };
    auto wread = [&](int c) {
#pragma unroll
        for (int nt = 0; nt < 4; ++nt)
            wr[c & 1][nt] = *(const f16x8*)(Wb1 + (c * 4 + nt) * 512);
    };
    auto l1mfma = [&](int c) {
        __builtin_amdgcn_s_setprio(1);
#pragma unroll
        for (int nt = 0; nt < 4; ++nt)
#pragma unroll
            for (int mt = 0; mt < 4; ++mt)
                acc[mt][nt] = __builtin_amdgcn_mfma_f32_16x16x32_f16(areg[c & 1][mt], wr[c & 1][nt], acc[mt][nt], 0, 0, 0);
        __builtin_amdgcn_s_setprio(0);
    };

    // ---------------- layer 1: [128x512] @ [512x256], 16 chunks ----------------
    // Schedule: store-distance 2 (chunk c+2 written in iter c) so A(c+1) is
    // ds_read-able in iter c; W(c+1) loaded in iter c. mfma(c) uses only regs
    // filled last iteration -> no exposed LDS/L2 latency inside the iteration.
    loadc(0, 0);
    loadc(1, 1);
    loadc(2, 2);
    storec(0, 0);
    storec(1, 1);
    wread(0);
    asm volatile("s_waitcnt lgkmcnt(0)" ::: "memory");
    __builtin_amdgcn_s_barrier();
    aread(0);
#pragma unroll
    for (int c = 0; c < 16; ++c) {
        if (c < 14) storec((c + 2) % 3, c + 2);
        if (c < 13) loadc((c + 3) % 3, c + 3);
        if (c < 15) {
            wread(c + 1);   // B-frags for next chunk: in flight under mfma(c)
            aread(c + 1);   // A-frags for next chunk (written iter c-1, post-barrier)
        }
        l1mfma(c);
        asm volatile("s_waitcnt lgkmcnt(0)" ::: "memory");
        __builtin_amdgcn_s_barrier();
    }
    __syncthreads();  // full drain before h overwrites the X union

    // bias + silu -> h1 (fp16 plane)
    {
        float bv[4];
#pragma unroll
        for (int nt = 0; nt < 4; ++nt) bv[nt] = b1[s * H + wn * 64 + nt * 16 + mh];
#pragma unroll
        for (int mt = 0; mt < 4; ++mt)
#pragma unroll
            for (int nt = 0; nt < 4; ++nt)
#pragma unroll
                for (int r = 0; r < 4; ++r) {
                    float v = acc[mt][nt][r] + bv[nt];
                    v = __fdividef(v, 1.f + __expf(-v));
                    hb[(wm * 64 + mt * 16 + g * 4 + r) * HSTR + wn * 64 + nt * 16 + mh] = (_Float16)v;
                    acc[mt][nt][r] = 0.f;
                }
    }
    __syncthreads();

    // ---------------- layers 2 and 3: [128x256] @ [256x256] ----------------
    for (int l = 0; l < 2; ++l) {
        const _Float16* Wb = l ? Wb3 : Wb2;
#pragma unroll
        for (int ks = 0; ks < 8; ++ks) {
            f16x8 a[4];
#pragma unroll
            for (int mt = 0; mt < 4; ++mt)
                a[mt] = *(const f16x8*)(hb + (wm * 64 + mt * 16 + mh) * HSTR + ks * 32 + g * 8);
            __builtin_amdgcn_s_setprio(1);
#pragma unroll
            for (int nt = 0; nt < 4; ++nt) {
                f16x8 b = *(const f16x8*)(Wb + (ks * 4 + nt) * 512);
#pragma unroll
                for (int mt = 0; mt < 4; ++mt)
                    acc[mt][nt] = __builtin_amdgcn_mfma_f32_16x16x32_f16(a[mt], b, acc[mt][nt], 0, 0, 0);
            }
            __builtin_amdgcn_s_setprio(0);
        }
        __syncthreads();  // all reads of h done before overwrite
        if (l == 0) {
            float bv[4];
#pragma unroll
            for (int nt = 0; nt < 4; ++nt) bv[nt] = b2[s * H + wn * 64 + nt * 16 + mh];
#pragma unroll
            for (int mt = 0; mt < 4; ++mt)
#pragma unroll
                for (int nt = 0; nt < 4; ++nt)
#pragma unroll
                    for (int r = 0; r < 4; ++r) {
                        float v = acc[mt][nt][r] + bv[nt];
                        v = __fdividef(v, 1.f + __expf(-v));
                        hb[(wm * 64 + mt * 16 + g * 4 + r) * HSTR + wn * 64 + nt * 16 + mh] = (_Float16)v;
                        acc[mt][nt][r] = 0.f;
                    }
            __syncthreads();
        }
    }

    // ---------------- layer 3 activation + layer 4 dot + reduce ----------------
    {
        float bv[4], w4v[4];
#pragma unroll
        for (int nt = 0; nt < 4; ++nt) {
            int col = wn * 64 + nt * 16 + mh;
            bv[nt] = b3[s * H + col];
            w4v[nt] = W4[s * H + col];
        }
#pragma unroll
        for (int mt = 0; mt < 4; ++mt)
#pragma unroll
            for (int r = 0; r < 4; ++r) {
                float v = 0.f;
#pragma unroll
                for (int nt = 0; nt < 4; ++nt) {
                    float h = acc[mt][nt][r] + bv[nt];
                    h = __fdividef(h, 1.f + __expf(-h));
                    v += h * w4v[nt];
                }
                v += __shfl_xor(v, 1);
                v += __shfl_xor(v, 2);
                v += __shfl_xor(v, 4);
                v += __shfl_xor(v, 8);
                if (mh == r) e_lds[wn][wm * 64 + mt * 16 + g * 4 + r] = v;
            }
    }
    __syncthreads();
    if (tid < BM) {
        float e = b4[s] + e_lds[0][tid] + e_lds[1][tid] + e_lds[2][tid] + e_lds[3][tid];
        Eout[(size_t)s * NATOMS + tile * BM + tid] = e;
    }
}

// stage 1: per-block private LDS histogram of 1024 atoms -> partial[512] per block
__global__ __launch_bounds__(256) void reduce1(
    const float* __restrict__ E, const int* __restrict__ ids,
    float* __restrict__ partials)
{
    __shared__ float tbl[NSTRUCT];
    const int b = blockIdx.x;
    const int tid = threadIdx.x;
    tbl[tid] = 0.f;
    tbl[tid + 256] = 0.f;
    __syncthreads();
    const int base = b * APB;
#pragma unroll
    for (int i = 0; i < APB / 256; ++i) {
        int a = base + i * 256 + tid;
        atomicAdd(&tbl[ids[a]], E[a]);
    }
    __syncthreads();
    partials[(size_t)b * NSTRUCT + tid] = tbl[tid];
    partials[(size_t)b * NSTRUCT + tid + 256] = tbl[tid + 256];
}

// stage 2: sum 128 partial tables + shift -> out
__global__ __launch_bounds__(512) void reduce2(
    const float* __restrict__ partials, const float* __restrict__ shift,
    float* __restrict__ out)
{
    const int i = threadIdx.x;
    float v = shift[0];
#pragma unroll 8
    for (int b = 0; b < RBLK; ++b) v += partials[(size_t)b * NSTRUCT + i];
    out[i] = v;
}

extern "C" void kernel_launch(void* const* d_in, const int* in_sizes, int n_in,
                              void* d_out, int out_size, void* d_ws, size_t ws_size,
                              hipStream_t stream) {
    const float* X   = (const float*)d_in[0];
    const int*   ids = (const int*)d_in[1];
    const float* W1  = (const float*)d_in[2];
    const float* b1  = (const float*)d_in[3];
    const float* W2  = (const float*)d_in[4];
    const float* b2  = (const float*)d_in[5];
    const float* W3  = (const float*)d_in[6];
    const float* b3  = (const float*)d_in[7];
    const float* W4  = (const float*)d_in[8];
    const float* b4  = (const float*)d_in[9];
    const float* shift = (const float*)d_in[10];

    // ws layout: W1p 1MB | W2p 512KB | W3p 512KB | E 512KB | partials 256KB
    _Float16* W1p = (_Float16*)d_ws;
    _Float16* W2p = W1p + (size_t)S * 4 * 64 * 512;
    _Float16* W3p = W2p + (size_t)S * 4 * 32 * 512;
    float* E = (float*)(W3p + (size_t)S * 4 * 32 * 512);
    float* partials = E + (size_t)S * NATOMS;

    pack_all<<<4096, 256, 0, stream>>>(W1, W2, W3, W1p, W2p, W3p);

    dim3 grid(NATOMS / BM, S);
    fused_mlp<<<grid, 512, 0, stream>>>(X, W1p, W2p, W3p, b1, b2, b3, W4, b4, E);

    reduce1<<<RBLK, 256, 0, stream>>>(E, ids, partials);
    reduce2<<<1, 512, 0, stream>>>(partials, shift, (float*)d_out);
}

// Round 18
// 152.604 us; speedup vs baseline: 1.2024x; 1.2024x over previous
//
#include <hip/hip_runtime.h>

typedef _Float16 f16x8 __attribute__((ext_vector_type(8)));
typedef _Float16 f16x4 __attribute__((ext_vector_type(4)));
typedef float f32x4 __attribute__((ext_vector_type(4)));

static constexpr int S = 4;
static constexpr int NATOMS = 32768;
static constexpr int FIN = 512;
static constexpr int H = 256;
static constexpr int BM = 128;   // atoms per block
static constexpr int XSTR = 36;  // 32 fp16 + 4 pad (72B rows: 2-way banks, free)
static constexpr int HSTR = 264; // h plane: 256 cols + 8 pad fp16 (528B rows, 2-way)
static constexpr int NSTRUCT = 512;
static constexpr int RBLK = 128;
static constexpr int APB = (S * NATOMS) / RBLK;  // 1024

// ---- merged weight packing: fp32 [S][K][H] -> per-(s,wn) consumption-order fp16
// Stream layout: [s*4 + (ntile>>2)][p][lane][8]; p = kt*4 + (ntile&3).
__global__ void pack_all(const float* __restrict__ W1, const float* __restrict__ W2,
                         const float* __restrict__ W3,
                         _Float16* __restrict__ W1p, _Float16* __restrict__ W2p,
                         _Float16* __restrict__ W3p) {
    int bid = blockIdx.x;
    const float* W;
    _Float16* dst;
    int KT, base;
    if (bid < 2048)      { W = W1; dst = W1p; KT = 16; base = 0; }
    else if (bid < 3072) { W = W2; dst = W2p; KT = 8;  base = 2048; }
    else                 { W = W3; dst = W3p; KT = 8;  base = 3072; }
    int idx = (bid - base) * 256 + threadIdx.x;
    int j = idx & 7;
    int lane = (idx >> 3) & 63;
    int rest = idx >> 9;
    int kt = rest % KT;
    int t2 = rest / KT;            // s*16 + ntile
    int K = KT * 32;
    int k = kt * 32 + (lane >> 4) * 8 + j;
    int ntile = t2 & 15;
    int s = t2 >> 4;
    int n = ntile * 16 + (lane & 15);
    int p = kt * 4 + (ntile & 3);
    size_t o = ((((size_t)(s * 4 + (ntile >> 2))) * (KT * 4) + p) * 64 + lane) * 8 + j;
    dst[o] = (_Float16)W[((size_t)s * K + k) * H + n];
}

// Register budget note: acc[4][4] = 64 AGPR + 64 arch VGPR = 128 total/wave.
// 8 waves/block x 2 blocks/CU = 4 waves/SIMD x 128 = 512 = the whole unified
// file. ANY extra VGPR drops residency to 1 block/CU (-20%, measured R14/R17).
__global__ __launch_bounds__(512, 3) void fused_mlp(
    const float* __restrict__ X,
    const _Float16* __restrict__ W1p, const _Float16* __restrict__ W2p,
    const _Float16* __restrict__ W3p,
    const float* __restrict__ b1, const float* __restrict__ b2,
    const float* __restrict__ b3,
    const float* __restrict__ W4, const float* __restrict__ b4,
    float* __restrict__ Eout)
{
    // union: X fp16 triple buffer [3][128][36] (27648B) aliased by h fp16 plane
    // [128][264] (67584B). h written only after all layer-1 LDS reads are done.
    __shared__ _Float16 smem[BM * HSTR];
    __shared__ float e_lds[4][BM];

    const int s = blockIdx.y;
    const int tile = blockIdx.x;
    const int tid = threadIdx.x;
    const int rw = __builtin_amdgcn_readfirstlane(tid >> 6);  // wave idx -> SGPR
    const int wm = rw >> 2;        // 0..1: M-half (64 atoms)
    const int wn = rw & 3;         // 0..3: 64-col slice of H
    const int lane = tid & 63;
    const int g = lane >> 4;
    const int mh = lane & 15;
    const int srow = tid >> 2;     // staging row (128 rows, 4 threads/row)
    const int cq = tid & 3;        // staging col group (8 floats)

    const float* Xb = X + (size_t)(s * NATOMS + tile * BM) * FIN;
    _Float16* hb = smem;

    // per-(s,wn) contiguous weight streams, shared by the wm-pair (L1 broadcast)
    const _Float16* Wb1 = W1p + ((size_t)(s * 4 + wn)) * (64 * 512) + lane * 8;
    const _Float16* Wb2 = W2p + ((size_t)(s * 4 + wn)) * (32 * 512) + lane * 8;
    const _Float16* Wb3 = W3p + ((size_t)(s * 4 + wn)) * (32 * 512) + lane * 8;

    f32x4 acc[4][4];
#pragma unroll
    for (int i = 0; i < 4; ++i)
#pragma unroll
        for (int j = 0; j < 4; ++j)
            acc[i][j] = f32x4{0.f, 0.f, 0.f, 0.f};

    // ---- layer-1 staging: global->reg (f32) -> cvt once -> LDS (f16) ----
    f32x4 ld[3][2];
    auto loadc = [&](int slot, int c) {
        const float* p = Xb + (size_t)srow * FIN + c * 32 + cq * 8;
        ld[slot][0] = *(const f32x4*)(p);
        ld[slot][1] = *(const f32x4*)(p + 4);
    };
    auto storec = [&](int slot, int c) {
        _Float16* xb = smem + (c % 3) * (BM * XSTR);
#pragma unroll
        for (int i = 0; i < 2; ++i) {
            f16x4 v;
#pragma unroll
            for (int j = 0; j < 4; ++j) v[j] = (_Float16)ld[slot][i][j];
            *(f16x4*)(xb + srow * XSTR + cq * 8 + i * 4) = v;
        }
    };
    auto l1mfma = [&](int c) {   // one MFMA-K (32) per chunk
        const _Float16* xb = smem + (c % 3) * (BM * XSTR);
        f16x8 a[4];
#pragma unroll
        for (int mt = 0; mt < 4; ++mt)
            a[mt] = *(const f16x8*)(xb + (wm * 64 + mt * 16 + mh) * XSTR + g * 8);
        __builtin_amdgcn_s_setprio(1);
#pragma unroll
        for (int nt = 0; nt < 4; ++nt) {
            f16x8 b = *(const f16x8*)(Wb1 + (c * 4 + nt) * 512);
#pragma unroll
            for (int mt = 0; mt < 4; ++mt)
                acc[mt][nt] = __builtin_amdgcn_mfma_f32_16x16x32_f16(a[mt], b, acc[mt][nt], 0, 0, 0);
        }
        __builtin_amdgcn_s_setprio(0);
    };

    // ---------------- layer 1: [128x512] @ [512x256], 16 chunks ----------------
    loadc(0, 0);
    loadc(1, 1);
    loadc(2, 2);
    storec(0, 0);
    asm volatile("s_waitcnt lgkmcnt(0)" ::: "memory");
    __builtin_amdgcn_s_barrier();
#pragma unroll
    for (int c = 0; c < 16; ++c) {
        if (c < 15) storec((c + 1) % 3, c + 1);  // slot holds chunk c+1 (loaded iter c-2)
        if (c < 13) loadc(c % 3, c + 3);         // slot's old chunk already in LDS
        l1mfma(c);
        asm volatile("s_waitcnt lgkmcnt(0)" ::: "memory");
        __builtin_amdgcn_s_barrier();
    }
    __syncthreads();  // full drain before h overwrites the X union

    // bias + silu -> h1 (fp16 plane)
    {
        float bv[4];
#pragma unroll
        for (int nt = 0; nt < 4; ++nt) bv[nt] = b1[s * H + wn * 64 + nt * 16 + mh];
#pragma unroll
        for (int mt = 0; mt < 4; ++mt)
#pragma unroll
            for (int nt = 0; nt < 4; ++nt)
#pragma unroll
                for (int r = 0; r < 4; ++r) {
                    float v = acc[mt][nt][r] + bv[nt];
                    v = __fdividef(v, 1.f + __expf(-v));
                    hb[(wm * 64 + mt * 16 + g * 4 + r) * HSTR + wn * 64 + nt * 16 + mh] = (_Float16)v;
                    acc[mt][nt][r] = 0.f;
                }
    }
    __syncthreads();

    // ---------------- layers 2 and 3: [128x256] @ [256x256] ----------------
    for (int l = 0; l < 2; ++l) {
        const _Float16* Wb = l ? Wb3 : Wb2;
#pragma unroll
        for (int ks = 0; ks < 8; ++ks) {
            f16x8 a[4];
#pragma unroll
            for (int mt = 0; mt < 4; ++mt)
                a[mt] = *(const f16x8*)(hb + (wm * 64 + mt * 16 + mh) * HSTR + ks * 32 + g * 8);
            __builtin_amdgcn_s_setprio(1);
#pragma unroll
            for (int nt = 0; nt < 4; ++nt) {
                f16x8 b = *(const f16x8*)(Wb + (ks * 4 + nt) * 512);
#pragma unroll
                for (int mt = 0; mt < 4; ++mt)
                    acc[mt][nt] = __builtin_amdgcn_mfma_f32_16x16x32_f16(a[mt], b, acc[mt][nt], 0, 0, 0);
            }
            __builtin_amdgcn_s_setprio(0);
        }
        __syncthreads();  // all reads of h done before overwrite
        if (l == 0) {
            float bv[4];
#pragma unroll
            for (int nt = 0; nt < 4; ++nt) bv[nt] = b2[s * H + wn * 64 + nt * 16 + mh];
#pragma unroll
            for (int mt = 0; mt < 4; ++mt)
#pragma unroll
                for (int nt = 0; nt < 4; ++nt)
#pragma unroll
                    for (int r = 0; r < 4; ++r) {
                        float v = acc[mt][nt][r] + bv[nt];
                        v = __fdividef(v, 1.f + __expf(-v));
                        hb[(wm * 64 + mt * 16 + g * 4 + r) * HSTR + wn * 64 + nt * 16 + mh] = (_Float16)v;
                        acc[mt][nt][r] = 0.f;
                    }
            __syncthreads();
        }
    }

    // ---------------- layer 3 activation + layer 4 dot + reduce ----------------
    {
        float bv[4], w4v[4];
#pragma unroll
        for (int nt = 0; nt < 4; ++nt) {
            int col = wn * 64 + nt * 16 + mh;
            bv[nt] = b3[s * H + col];
            w4v[nt] = W4[s * H + col];
        }
#pragma unroll
        for (int mt = 0; mt < 4; ++mt)
#pragma unroll
            for (int r = 0; r < 4; ++r) {
                float v = 0.f;
#pragma unroll
                for (int nt = 0; nt < 4; ++nt) {
                    float h = acc[mt][nt][r] + bv[nt];
                    h = __fdividef(h, 1.f + __expf(-h));
                    v += h * w4v[nt];
                }
                v += __shfl_xor(v, 1);
                v += __shfl_xor(v, 2);
                v += __shfl_xor(v, 4);
                v += __shfl_xor(v, 8);
                if (mh == r) e_lds[wn][wm * 64 + mt * 16 + g * 4 + r] = v;
            }
    }
    __syncthreads();
    // plain coalesced store of per-atom energies -- no global atomics
    if (tid < BM) {
        float e = b4[s] + e_lds[0][tid] + e_lds[1][tid] + e_lds[2][tid] + e_lds[3][tid];
        Eout[(size_t)s * NATOMS + tile * BM + tid] = e;
    }
}

// stage 1: per-block private LDS histogram of 1024 atoms -> partial[512] per block
__global__ __launch_bounds__(256) void reduce1(
    const float* __restrict__ E, const int* __restrict__ ids,
    float* __restrict__ partials)
{
    __shared__ float tbl[NSTRUCT];
    const int b = blockIdx.x;
    const int tid = threadIdx.x;
    tbl[tid] = 0.f;
    tbl[tid + 256] = 0.f;
    __syncthreads();
    const int base = b * APB;
#pragma unroll
    for (int i = 0; i < APB / 256; ++i) {
        int a = base + i * 256 + tid;
        atomicAdd(&tbl[ids[a]], E[a]);
    }
    __syncthreads();
    partials[(size_t)b * NSTRUCT + tid] = tbl[tid];
    partials[(size_t)b * NSTRUCT + tid + 256] = tbl[tid + 256];
}

// stage 2: sum 128 partial tables + shift -> out
__global__ __launch_bounds__(512) void reduce2(
    const float* __restrict__ partials, const float* __restrict__ shift,
    float* __restrict__ out)
{
    const int i = threadIdx.x;
    float v = shift[0];
#pragma unroll 8
    for (int b = 0; b < RBLK; ++b) v += partials[(size_t)b * NSTRUCT + i];
    out[i] = v;
}

extern "C" void kernel_launch(void* const* d_in, const int* in_sizes, int n_in,
                              void* d_out, int out_size, void* d_ws, size_t ws_size,
                              hipStream_t stream) {
    const float* X   = (const float*)d_in[0];
    const int*   ids = (const int*)d_in[1];
    const float* W1  = (const float*)d_in[2];
    const float* b1  = (const float*)d_in[3];
    const float* W2  = (const float*)d_in[4];
    const float* b2  = (const float*)d_in[5];
    const float* W3  = (const float*)d_in[6];
    const float* b3  = (const float*)d_in[7];
    const float* W4  = (const float*)d_in[8];
    const float* b4  = (const float*)d_in[9];
    const float* shift = (const float*)d_in[10];

    // ws layout: W1p 1MB | W2p 512KB | W3p 512KB | E 512KB | partials 256KB
    _Float16* W1p = (_Float16*)d_ws;
    _Float16* W2p = W1p + (size_t)S * 4 * 64 * 512;
    _Float16* W3p = W2p + (size_t)S * 4 * 32 * 512;
    float* E = (float*)(W3p + (size_t)S * 4 * 32 * 512);
    float* partials = E + (size_t)S * NATOMS;

    pack_all<<<4096, 256, 0, stream>>>(W1, W2, W3, W1p, W2p, W3p);

    dim3 grid(NATOMS / BM, S);
    fused_mlp<<<grid, 512, 0, stream>>>(X, W1p, W2p, W3p, b1, b2, b3, W4, b4, E);

    reduce1<<<RBLK, 256, 0, stream>>>(E, ids, partials);
    reduce2<<<1, 512, 0, stream>>>(partials, shift, (float*)d_out);
}

// Round 19
// 141.258 us; speedup vs baseline: 1.2990x; 1.0803x over previous
//
#include <hip/hip_runtime.h>

typedef _Float16 f16x8 __attribute__((ext_vector_type(8)));
typedef _Float16 f16x4 __attribute__((ext_vector_type(4)));
typedef float f32x4 __attribute__((ext_vector_type(4)));

static constexpr int S = 4;
static constexpr int NATOMS = 32768;
static constexpr int FIN = 512;
static constexpr int H = 256;
static constexpr int BM = 64;    // atoms per block
static constexpr int XSTR = 72;  // fp16/row (144B): 2-way banks, free
static constexpr int HSTR = 264; // h plane: 256 cols + 8 pad fp16 (528B rows, 2-way)
static constexpr int NSTRUCT = 512;
static constexpr int RBLK = 128;
static constexpr int APB = (S * NATOMS) / RBLK;  // 1024

// ---- merged weight packing: fp32 [S][K][H] -> per-wave consumption-order fp16
// Stream layout: [s][wn=ntile>>1][p][lane][8].
// L1 (KT=16): p = (kt>>1)*4 + (kt&1)*2 + (ntile&1)   (kernel order: c, ks, nt)
// L2/L3 (KT=8): p = kt*2 + (ntile&1)
__global__ void pack_all(const float* __restrict__ W1, const float* __restrict__ W2,
                         const float* __restrict__ W3,
                         _Float16* __restrict__ W1p, _Float16* __restrict__ W2p,
                         _Float16* __restrict__ W3p) {
    int bid = blockIdx.x;
    const float* W;
    _Float16* dst;
    int KT, l1, base;
    if (bid < 2048)      { W = W1; dst = W1p; KT = 16; l1 = 1; base = 0; }
    else if (bid < 3072) { W = W2; dst = W2p; KT = 8;  l1 = 0; base = 2048; }
    else                 { W = W3; dst = W3p; KT = 8;  l1 = 0; base = 3072; }
    int idx = (bid - base) * 256 + threadIdx.x;
    int j = idx & 7;
    int lane = (idx >> 3) & 63;
    int rest = idx >> 9;
    int kt = rest % KT;
    int t2 = rest / KT;            // s*16 + ntile
    int K = KT * 32;
    int k = kt * 32 + (lane >> 4) * 8 + j;
    int ntile = t2 & 15;
    int s = t2 >> 4;
    int n = ntile * 16 + (lane & 15);
    int p = l1 ? ((kt >> 1) * 4 + (kt & 1) * 2 + (ntile & 1))
               : (kt * 2 + (ntile & 1));
    size_t o = ((((size_t)(s * 8 + (ntile >> 1))) * (KT * 2) + p) * 64 + lane) * 8 + j;
    dst[o] = (_Float16)W[((size_t)s * K + k) * H + n];
}

// Register budget note: acc[4][2]=32 AGPR + ~52 VGPR = 84 total/wave ->
// 6 waves/SIMD possible -> 3 blocks/CU resident (measured 42-45% occupancy,
// best bench of the session). Do not grow per-wave state.
__global__ __launch_bounds__(512, 4) void fused_mlp(
    const float* __restrict__ X,
    const _Float16* __restrict__ W1p, const _Float16* __restrict__ W2p,
    const _Float16* __restrict__ W3p,
    const float* __restrict__ b1, const float* __restrict__ b2,
    const float* __restrict__ b3,
    const float* __restrict__ W4, const float* __restrict__ b4,
    float* __restrict__ Eout)
{
    // union: X fp16 triple buffer [3][64][72] (27648B) aliased by h fp16 plane
    // [64][264] (33792B). h written only after all layer-1 LDS reads are done.
    __shared__ _Float16 smem[BM * HSTR];
    __shared__ float e_lds[8][BM];

    const int s = blockIdx.y;
    const int tile = blockIdx.x;
    const int tid = threadIdx.x;
    const int rw = __builtin_amdgcn_readfirstlane(tid >> 6);  // wave idx -> SGPR
    const int lane = tid & 63;
    const int g = lane >> 4;
    const int mh = lane & 15;
    const int srow = tid >> 3;     // staging row (64 rows, 8 threads/row)
    const int cq = tid & 7;        // staging col group (8 floats each)

    const float* Xb = X + (size_t)(s * NATOMS + tile * BM) * FIN;
    _Float16* hb = smem;

    // per-wave contiguous weight streams (SGPR base + lane*16B + constexpr imm)
    const _Float16* Wb1 = W1p + ((size_t)(s * 8 + rw)) * (32 * 512) + lane * 8;
    const _Float16* Wb2 = W2p + ((size_t)(s * 8 + rw)) * (16 * 512) + lane * 8;
    const _Float16* Wb3 = W3p + ((size_t)(s * 8 + rw)) * (16 * 512) + lane * 8;

    f32x4 acc[4][2];
#pragma unroll
    for (int i = 0; i < 4; ++i)
#pragma unroll
        for (int j = 0; j < 2; ++j)
            acc[i][j] = f32x4{0.f, 0.f, 0.f, 0.f};

    // ---- layer-1 staging: global->reg (f32) -> cvt once -> LDS (f16) ----
    f32x4 ld[3][2];
    auto loadc = [&](int slot, int c) {
        const float* p = Xb + (size_t)srow * FIN + c * 64 + cq * 8;
        ld[slot][0] = *(const f32x4*)(p);
        ld[slot][1] = *(const f32x4*)(p + 4);
    };
    auto storec = [&](int slot, int c) {
        _Float16* xb = smem + (c % 3) * (BM * XSTR);
#pragma unroll
        for (int i = 0; i < 2; ++i) {
            f16x4 v;
#pragma unroll
            for (int j = 0; j < 4; ++j) v[j] = (_Float16)ld[slot][i][j];
            *(f16x4*)(xb + srow * XSTR + cq * 8 + i * 4) = v;
        }
    };
    // A-fragment: ONE ds_read_b128 feeding MFMA directly
    auto l1mfma = [&](int c) {
        const _Float16* xb = smem + (c % 3) * (BM * XSTR);
#pragma unroll
        for (int ks = 0; ks < 2; ++ks) {
            f16x8 a[4];
#pragma unroll
            for (int mt = 0; mt < 4; ++mt)
                a[mt] = *(const f16x8*)(xb + (mt * 16 + mh) * XSTR + (ks * 4 + g) * 8);
            __builtin_amdgcn_s_setprio(1);
#pragma unroll
            for (int nt = 0; nt < 2; ++nt) {
                f16x8 b = *(const f16x8*)(Wb1 + (c * 4 + ks * 2 + nt) * 512);
#pragma unroll
                for (int mt = 0; mt < 4; ++mt)
                    acc[mt][nt] = __builtin_amdgcn_mfma_f32_16x16x32_f16(a[mt], b, acc[mt][nt], 0, 0, 0);
            }
            __builtin_amdgcn_s_setprio(0);
        }
    };

    // ---------------- layer 1: [64x512] @ [512x256] ----------------
    // Reg slots hold chunks ~2 iterations ahead; raw s_barrier waits only
    // lgkmcnt(0) (ds_writes visible) -- global loads stay in flight across it.
    loadc(0, 0);
    loadc(1, 1);
    loadc(2, 2);
    storec(0, 0);
    asm volatile("s_waitcnt lgkmcnt(0)" ::: "memory");
    __builtin_amdgcn_s_barrier();
#pragma unroll
    for (int c = 0; c < 8; ++c) {
        if (c < 7) storec((c + 1) % 3, c + 1);  // slot holds chunk c+1 (loaded iter c-2)
        if (c < 5) loadc(c % 3, c + 3);         // slot's old chunk already in LDS
        l1mfma(c);
        asm volatile("s_waitcnt lgkmcnt(0)" ::: "memory");
        __builtin_amdgcn_s_barrier();
    }
    __syncthreads();  // full drain before h overwrites the X union

    // bias + silu -> h1 (fp16 plane)
    {
        float bv[2];
#pragma unroll
        for (int nt = 0; nt < 2; ++nt) bv[nt] = b1[s * H + rw * 32 + nt * 16 + mh];
#pragma unroll
        for (int mt = 0; mt < 4; ++mt)
#pragma unroll
            for (int nt = 0; nt < 2; ++nt)
#pragma unroll
                for (int r = 0; r < 4; ++r) {
                    float v = acc[mt][nt][r] + bv[nt];
                    v = __fdividef(v, 1.f + __expf(-v));
                    hb[(mt * 16 + g * 4 + r) * HSTR + rw * 32 + nt * 16 + mh] = (_Float16)v;
                    acc[mt][nt][r] = 0.f;
                }
    }
    __syncthreads();

    // ---------------- layers 2 and 3: [64x256] @ [256x256] ----------------
    for (int l = 0; l < 2; ++l) {
        const _Float16* Wb = l ? Wb3 : Wb2;
#pragma unroll
        for (int ks = 0; ks < 8; ++ks) {
            f16x8 a[4];
#pragma unroll
            for (int mt = 0; mt < 4; ++mt)
                a[mt] = *(const f16x8*)(hb + (mt * 16 + mh) * HSTR + ks * 32 + g * 8);
            __builtin_amdgcn_s_setprio(1);
#pragma unroll
            for (int nt = 0; nt < 2; ++nt) {
                f16x8 b = *(const f16x8*)(Wb + (ks * 2 + nt) * 512);
#pragma unroll
                for (int mt = 0; mt < 4; ++mt)
                    acc[mt][nt] = __builtin_amdgcn_mfma_f32_16x16x32_f16(a[mt], b, acc[mt][nt], 0, 0, 0);
            }
            __builtin_amdgcn_s_setprio(0);
        }
        __syncthreads();  // all reads of h done before overwrite
        if (l == 0) {
            float bv[2];
#pragma unroll
            for (int nt = 0; nt < 2; ++nt) bv[nt] = b2[s * H + rw * 32 + nt * 16 + mh];
#pragma unroll
            for (int mt = 0; mt < 4; ++mt)
#pragma unroll
                for (int nt = 0; nt < 2; ++nt)
#pragma unroll
                    for (int r = 0; r < 4; ++r) {
                        float v = acc[mt][nt][r] + bv[nt];
                        v = __fdividef(v, 1.f + __expf(-v));
                        hb[(mt * 16 + g * 4 + r) * HSTR + rw * 32 + nt * 16 + mh] = (_Float16)v;
                        acc[mt][nt][r] = 0.f;
                    }
            __syncthreads();
        }
    }

    // ---------------- layer 3 activation + layer 4 dot + reduce ----------------
    {
        float bv[2], w4v[2];
#pragma unroll
        for (int nt = 0; nt < 2; ++nt) {
            int col = rw * 32 + nt * 16 + mh;
            bv[nt] = b3[s * H + col];
            w4v[nt] = W4[s * H + col];
        }
#pragma unroll
        for (int mt = 0; mt < 4; ++mt)
#pragma unroll
            for (int r = 0; r < 4; ++r) {
                float v = 0.f;
#pragma unroll
                for (int nt = 0; nt < 2; ++nt) {
                    float h = acc[mt][nt][r] + bv[nt];
                    h = __fdividef(h, 1.f + __expf(-h));
                    v += h * w4v[nt];
                }
                v += __shfl_xor(v, 1);
                v += __shfl_xor(v, 2);
                v += __shfl_xor(v, 4);
                v += __shfl_xor(v, 8);
                if (mh == r) e_lds[rw][mt * 16 + g * 4 + r] = v;
            }
    }
    __syncthreads();
    // plain coalesced store of per-atom energies -- no global atomics
    if (tid < BM) {
        float e = b4[s];
#pragma unroll
        for (int j = 0; j < 8; ++j) e += e_lds[j][tid];
        Eout[(size_t)s * NATOMS + tile * BM + tid] = e;
    }
}

// stage 1: per-block private LDS histogram of 1024 atoms -> partial[512] per block
__global__ __launch_bounds__(256) void reduce1(
    const float* __restrict__ E, const int* __restrict__ ids,
    float* __restrict__ partials)
{
    __shared__ float tbl[NSTRUCT];
    const int b = blockIdx.x;
    const int tid = threadIdx.x;
    tbl[tid] = 0.f;
    tbl[tid + 256] = 0.f;
    __syncthreads();
    const int base = b * APB;
#pragma unroll
    for (int i = 0; i < APB / 256; ++i) {
        int a = base + i * 256 + tid;
        atomicAdd(&tbl[ids[a]], E[a]);
    }
    __syncthreads();
    partials[(size_t)b * NSTRUCT + tid] = tbl[tid];
    partials[(size_t)b * NSTRUCT + tid + 256] = tbl[tid + 256];
}

// stage 2: sum 128 partial tables + shift -> out
__global__ __launch_bounds__(512) void reduce2(
    const float* __restrict__ partials, const float* __restrict__ shift,
    float* __restrict__ out)
{
    const int i = threadIdx.x;
    float v = shift[0];
#pragma unroll 8
    for (int b = 0; b < RBLK; ++b) v += partials[(size_t)b * NSTRUCT + i];
    out[i] = v;
}

extern "C" void kernel_launch(void* const* d_in, const int* in_sizes, int n_in,
                              void* d_out, int out_size, void* d_ws, size_t ws_size,
                              hipStream_t stream) {
    const float* X   = (const float*)d_in[0];
    const int*   ids = (const int*)d_in[1];
    const float* W1  = (const float*)d_in[2];
    const float* b1  = (const float*)d_in[3];
    const float* W2  = (const float*)d_in[4];
    const float* b2  = (const float*)d_in[5];
    const float* W3  = (const float*)d_in[6];
    const float* b3  = (const float*)d_in[7];
    const float* W4  = (const float*)d_in[8];
    const float* b4  = (const float*)d_in[9];
    const float* shift = (const float*)d_in[10];

    // ws layout: W1p 1MB | W2p 512KB | W3p 512KB | E 512KB | partials 256KB
    _Float16* W1p = (_Float16*)d_ws;
    _Float16* W2p = W1p + (size_t)S * 8 * 32 * 512;
    _Float16* W3p = W2p + (size_t)S * 8 * 16 * 512;
    float* E = (float*)(W3p + (size_t)S * 8 * 16 * 512);
    float* partials = E + (size_t)S * NATOMS;

    pack_all<<<4096, 256, 0, stream>>>(W1, W2, W3, W1p, W2p, W3p);

    dim3 grid(NATOMS / BM, S);
    fused_mlp<<<grid, 512, 0, stream>>>(X, W1p, W2p, W3p, b1, b2, b3, W4, b4, E);

    reduce1<<<RBLK, 256, 0, stream>>>(E, ids, partials);
    reduce2<<<1, 512, 0, stream>>>(partials, shift, (float*)d_out);
}